// Round 14
// baseline (210.246 us; speedup 1.0000x reference)
//
#include <hip/hip_runtime.h>

typedef __attribute__((ext_vector_type(8))) short bf16x8;
typedef __attribute__((ext_vector_type(4))) float f32x4;
typedef unsigned int uint;
typedef unsigned short ushort;

#define NFEAT 128

__device__ __forceinline__ ushort f2b(float f) {
    uint u = __float_as_uint(f);
    u = (u + 0x7fffu + ((u >> 16) & 1u)) >> 16;   // RNE
    return (ushort)u;
}

// async global->LDS, 16B per lane; lds base must be wave-uniform (HW adds lane*16)
__device__ __forceinline__ void gload_lds16(const ushort* g, char* lds) {
    __builtin_amdgcn_global_load_lds((const __attribute__((address_space(1))) void*)g,
                                     (__attribute__((address_space(3))) void*)lds, 16, 0, 0);
}

// ---------------- merged prep: x->bf16 convert | weight prep | degree histogram ----
__global__ __launch_bounds__(256) void prep(
    const float* __restrict__ x, ushort* __restrict__ x_bf, long nx,
    const float* __restrict__ w1l, const float* __restrict__ w1r,
    const float* __restrict__ w2l, const float* __restrict__ w2r,
    const float* __restrict__ wd,
    ushort* __restrict__ wc1, ushort* __restrict__ wc2, ushort* __restrict__ wdec,
    const int* __restrict__ dst, int* __restrict__ deg, int E, int nCvt)
{
    const int b = blockIdx.x;
    if (b < nCvt) {
        long i = ((long)b * 256 + threadIdx.x) * 4;
        if (i < nx) {
            float4 v = *(const float4*)(x + i);
            ushort4 o;
            o.x = f2b(v.x); o.y = f2b(v.y); o.z = f2b(v.z); o.w = f2b(v.w);
            *(ushort4*)(x_bf + i) = o;
        }
    } else if (b < nCvt + 256) {
        const int bb = b - nCvt;
        const int i = (bb & 127) * 256 + threadIdx.x;
        const int row = i >> 8, col = i & 255;
        const float* wl = (bb < 128) ? w1l : w2l;
        const float* wr = (bb < 128) ? w1r : w2r;
        ushort* dstw = (bb < 128) ? wc1 : wc2;
        float v = (col < 128) ? wl[row * 128 + col] : wr[row * 128 + col - 128];
        dstw[i] = f2b(v);
    } else if (b < nCvt + 320) {
        const int i = (b - nCvt - 256) * 256 + threadIdx.x;   // 64*256 = 16384
        wdec[i] = f2b(wd[i]);
    } else {
        const int e = (b - nCvt - 320) * 256 + threadIdx.x;
        if (e < E) atomicAdd(&deg[dst[e]], 1);
    }
}

// ---------------- exclusive scan: block-local pass ----------------
__global__ __launch_bounds__(256) void scan_blocks(const int* __restrict__ in, int* __restrict__ out,
                                                   int* __restrict__ bsum, int n) {
    __shared__ int lds[256];
    const int t = threadIdx.x;
    const int base = blockIdx.x * 1024 + t * 4;
    int a[4];
#pragma unroll
    for (int q = 0; q < 4; ++q) a[q] = (base + q < n) ? in[base + q] : 0;
    const int tsum = a[0] + a[1] + a[2] + a[3];
    lds[t] = tsum;
    __syncthreads();
    for (int off = 1; off < 256; off <<= 1) {
        int v = (t >= off) ? lds[t - off] : 0;
        __syncthreads();
        lds[t] += v;
        __syncthreads();
    }
    const int excl = lds[t] - tsum;
    if (t == 255) bsum[blockIdx.x] = lds[255];
    int r = excl;
#pragma unroll
    for (int q = 0; q < 4; ++q) {
        if (base + q < n) out[base + q] = r;
        r += a[q];
    }
}

// ---------------- scan finalize: inline carry (wave all-reduce over bsum prefix) ----
__global__ __launch_bounds__(256) void scan_add(int* __restrict__ row_off, int* __restrict__ pos,
                                                const int* __restrict__ bsum, int n, int E) {
    const int i = blockIdx.x * 256 + threadIdx.x;
    const int cb = blockIdx.x >> 2;
    const int lane = threadIdx.x & 63;
    int v = 0;
    if (lane < cb) v += bsum[lane];
    if (lane + 64 < cb) v += bsum[lane + 64];
#pragma unroll
    for (int off = 1; off < 64; off <<= 1) v += __shfl_xor(v, off);
    if (i < n) {
        const int r = row_off[i] + v;
        row_off[i] = r;
        pos[i] = r;
    }
    if (i == 0) row_off[n] = E;
}

// ---------------- CSR bucket fill ----------------
__global__ void fill_csr(const int* __restrict__ src, const int* __restrict__ dst,
                         int* __restrict__ pos, int* __restrict__ perm, int E) {
    const int e = blockIdx.x * blockDim.x + threadIdx.x;
    if (e < E) {
        const int p = atomicAdd(&pos[dst[e]], 1);
        perm[p] = src[e];
    }
}

// ---------------- gather helpers: 4-edge and 1-edge accumulate (constant-indexed) --
__device__ __forceinline__ void acc4(const int* __restrict__ perm, int i,
                                     const ushort* __restrict__ fp, float* acc) {
    int s[4];
#pragma unroll
    for (int k = 0; k < 4; ++k) s[k] = perm[i + k];
    uint4 v[4];
#pragma unroll
    for (int k = 0; k < 4; ++k) v[k] = *(const uint4*)(fp + (size_t)s[k] * NFEAT);
#pragma unroll
    for (int k = 0; k < 4; ++k) {
        const uint p[4] = {v[k].x, v[k].y, v[k].z, v[k].w};
#pragma unroll
        for (int q = 0; q < 4; ++q) {
            acc[2 * q]     += __uint_as_float(p[q] << 16);
            acc[2 * q + 1] += __uint_as_float(p[q] & 0xffff0000u);
        }
    }
}
__device__ __forceinline__ void acc1(const int* __restrict__ perm, int i,
                                     const ushort* __restrict__ fp, float* acc) {
    const int s = perm[i];
    const uint4 v = *(const uint4*)(fp + (size_t)s * NFEAT);
    const uint p[4] = {v.x, v.y, v.z, v.w};
#pragma unroll
    for (int q = 0; q < 4; ++q) {
        acc[2 * q]     += __uint_as_float(p[q] << 16);
        acc[2 * q + 1] += __uint_as_float(p[q] & 0xffff0000u);
    }
}

// ---------------- gather mean: 16-lane group owns TWO adjacent nodes ---------------
// Dual-stream main loop issues 8 independent row-loads per iteration (vs 4), all
// useful (r12's masked depth-8 wasted ~25% on short rows). Per-node accumulation
// order is identical to the single-node version -> bit-identical results.
__global__ __launch_bounds__(256) void gather_mean_bf(const int* __restrict__ row_off,
                                                      const int* __restrict__ perm,
                                                      const ushort* __restrict__ feat,
                                                      ushort* __restrict__ out, int n) {
    const int g = (blockIdx.x * 256 + threadIdx.x) >> 4;
    const int n0 = g * 2;
    if (n0 >= n) return;
    const int chunk = threadIdx.x & 15;
    const ushort* fp = feat + chunk * 8;
    const int n1 = n0 + 1;
    const bool has1 = (n1 < n);
    const int lo0 = row_off[n0], hi0 = row_off[n0 + 1];
    const int lo1 = has1 ? row_off[n1] : 0;
    const int hi1 = has1 ? row_off[n1 + 1] : 0;
    float a0[8] = {0.f, 0.f, 0.f, 0.f, 0.f, 0.f, 0.f, 0.f};
    float a1[8] = {0.f, 0.f, 0.f, 0.f, 0.f, 0.f, 0.f, 0.f};
    int i0 = lo0, i1 = lo1;
    // dual-stream: 8 loads in flight
    while (i0 + 3 < hi0 && i1 + 3 < hi1) {
        int s0[4], s1[4];
#pragma unroll
        for (int k = 0; k < 4; ++k) s0[k] = perm[i0 + k];
#pragma unroll
        for (int k = 0; k < 4; ++k) s1[k] = perm[i1 + k];
        uint4 v0[4], v1[4];
#pragma unroll
        for (int k = 0; k < 4; ++k) v0[k] = *(const uint4*)(fp + (size_t)s0[k] * NFEAT);
#pragma unroll
        for (int k = 0; k < 4; ++k) v1[k] = *(const uint4*)(fp + (size_t)s1[k] * NFEAT);
#pragma unroll
        for (int k = 0; k < 4; ++k) {
            const uint p0[4] = {v0[k].x, v0[k].y, v0[k].z, v0[k].w};
            const uint p1[4] = {v1[k].x, v1[k].y, v1[k].z, v1[k].w};
#pragma unroll
            for (int q = 0; q < 4; ++q) {
                a0[2 * q]     += __uint_as_float(p0[q] << 16);
                a0[2 * q + 1] += __uint_as_float(p0[q] & 0xffff0000u);
                a1[2 * q]     += __uint_as_float(p1[q] << 16);
                a1[2 * q + 1] += __uint_as_float(p1[q] & 0xffff0000u);
            }
        }
        i0 += 4; i1 += 4;
    }
    // drain stream 0
    for (; i0 + 3 < hi0; i0 += 4) acc4(perm, i0, fp, a0);
    for (; i0 < hi0; ++i0)        acc1(perm, i0, fp, a0);
    // drain stream 1
    for (; i1 + 3 < hi1; i1 += 4) acc4(perm, i1, fp, a1);
    for (; i1 < hi1; ++i1)        acc1(perm, i1, fp, a1);

    {
        const float inv = 1.0f / fmaxf((float)(hi0 - lo0), 1.0f);
        ushort o[8] __attribute__((aligned(16)));
#pragma unroll
        for (int q = 0; q < 8; ++q) o[q] = f2b(a0[q] * inv);
        *(uint4*)(out + (size_t)n0 * NFEAT + chunk * 8) = *(const uint4*)o;
    }
    if (has1) {
        const float inv = 1.0f / fmaxf((float)(hi1 - lo1), 1.0f);
        ushort o[8] __attribute__((aligned(16)));
#pragma unroll
        for (int q = 0; q < 8; ++q) o[q] = f2b(a1[q] * inv);
        *(uint4*)(out + (size_t)n1 * NFEAT + chunk * 8) = *(const uint4*)o;
    }
}

// ---------------- bf16 MFMA GEMM (staged via global_load_lds) + optional decoder ----
// out[row][col] = sum_k A[row][k] * Wcat[col][k] + bias[col]   (A = [mean|xin], K=256)
// Staging: global_load_lds width=16, LINEAR LDS dest (wave base + lane*16), the
// XOR-swizzle applied to the GLOBAL source chunk index (c = pc ^ (row&7)) so the
// swizzled ds_read side is unchanged (rule: both-sides-or-neither).
// Swapped MFMA operands: C layout row=lane&15 (node row), col=(lane>>4)*4+reg.
template <bool RELU, bool DEC>
__global__ __launch_bounds__(256) void sage_mfma(
    const ushort* __restrict__ Amean, const ushort* __restrict__ Axin,
    const ushort* __restrict__ Wcat, const float* __restrict__ bias,
    const ushort* __restrict__ Wdec, const float* __restrict__ bdec,
    float* __restrict__ outf, ushort* __restrict__ outb,
    float* __restrict__ dxp, int n)
{
    __shared__ uint4 smem4[2048];            // 32 KiB
    char* As = (char*)smem4;                 // [128 rows][64 bf16] swizzled
    char* Ws = As + 16384;
    const int t = threadIdx.x;
    const int m0 = blockIdx.x * 128;
    const int lane = t & 63;
    const int wid = t >> 6;
    const int lrow = lane & 15;
    const int lq = lane >> 4;

    f32x4 acc[2][8];
#pragma unroll
    for (int m = 0; m < 2; ++m)
#pragma unroll
        for (int nn = 0; nn < 8; ++nn) acc[m][nn] = (f32x4){0.f, 0.f, 0.f, 0.f};

    for (int kt = 0; kt < 4; ++kt) {
        const ushort* Abase = (kt < 2) ? Amean : Axin;
        const int co = (kt & 1) * 64;
        // ---- stage A and W tiles: 4 x 1KB wave-uniform chunks each
#pragma unroll
        for (int i = 0; i < 4; ++i) {
            const int row = i * 32 + wid * 8 + (lane >> 3);  // this lane's dest row
            const int c = (lane & 7) ^ (row & 7);            // pre-swizzled source chunk
            int gm = m0 + row;
            if (gm >= n) gm = n - 1;                         // clamp; masked at epilogue
            gload_lds16(Abase + (size_t)gm * NFEAT + co + c * 8,
                        As + i * 4096 + wid * 1024);
            gload_lds16(Wcat + (size_t)row * 256 + kt * 64 + c * 8,
                        Ws + i * 4096 + wid * 1024);
        }
        __syncthreads();
#pragma unroll
        for (int ks = 0; ks < 2; ++ks) {
            bf16x8 af[2], bfr[8];
#pragma unroll
            for (int m = 0; m < 2; ++m) {
                const int row = wid * 32 + m * 16 + lrow;
                af[m] = *(const bf16x8*)(As + row * 128 + (((ks * 4 + lq) * 16) ^ ((row & 7) << 4)));
            }
#pragma unroll
            for (int nn = 0; nn < 8; ++nn) {
                const int row = nn * 16 + lrow;
                bfr[nn] = *(const bf16x8*)(Ws + row * 128 + (((ks * 4 + lq) * 16) ^ ((row & 7) << 4)));
            }
#pragma unroll
            for (int m = 0; m < 2; ++m)
#pragma unroll
                for (int nn = 0; nn < 8; ++nn)
                    acc[m][nn] = __builtin_amdgcn_mfma_f32_16x16x32_bf16(bfr[nn], af[m], acc[m][nn], 0, 0, 0);
        }
        __syncthreads();
    }
    // ---- h epilogue (swapped C layout): node row = lane&15, cols = lq*4 + r
    char* Lh = As;   // DEC: [128 rows][128 bf16] swizzled, wave-private quarters
#pragma unroll
    for (int m = 0; m < 2; ++m) {
        const int row = wid * 32 + m * 16 + lrow;
        const int grow = m0 + row;
#pragma unroll
        for (int nn = 0; nn < 8; ++nn) {
            const int colb = nn * 16 + lq * 4;
            const float4 bv = *(const float4*)(bias + colb);
            float v0 = acc[m][nn][0] + bv.x;
            float v1 = acc[m][nn][1] + bv.y;
            float v2 = acc[m][nn][2] + bv.z;
            float v3 = acc[m][nn][3] + bv.w;
            if (RELU) {
                v0 = fmaxf(v0, 0.f); v1 = fmaxf(v1, 0.f);
                v2 = fmaxf(v2, 0.f); v3 = fmaxf(v3, 0.f);
            }
            ushort4 ob;
            ob.x = f2b(v0); ob.y = f2b(v1); ob.z = f2b(v2); ob.w = f2b(v3);
            if (grow < n) {
                if (outf) *(float4*)(outf + (size_t)grow * NFEAT + colb) = make_float4(v0, v1, v2, v3);
                if (outb) *(ushort4*)(outb + (size_t)grow * NFEAT + colb) = ob;
            }
            if (DEC)
                *(ushort4*)(Lh + row * 256 + ((colb * 2) ^ ((row & 7) << 4))) = ob;
        }
    }
    if (DEC) {
        // wave-private quarters: no barrier needed
        f32x4 acc2[2][8];
#pragma unroll
        for (int m = 0; m < 2; ++m)
#pragma unroll
            for (int nn = 0; nn < 8; ++nn) acc2[m][nn] = (f32x4){0.f, 0.f, 0.f, 0.f};
#pragma unroll
        for (int ks = 0; ks < 4; ++ks) {
            bf16x8 af2[2], bf2[8];
#pragma unroll
            for (int m = 0; m < 2; ++m) {
                const int row = wid * 32 + m * 16 + lrow;
                af2[m] = *(const bf16x8*)(Lh + row * 256 + ((ks * 64 + lq * 16) ^ ((row & 7) << 4)));
            }
#pragma unroll
            for (int nn = 0; nn < 8; ++nn)
                bf2[nn] = *(const bf16x8*)(Wdec + (size_t)(nn * 16 + lrow) * NFEAT + ks * 32 + lq * 8);
#pragma unroll
            for (int m = 0; m < 2; ++m)
#pragma unroll
                for (int nn = 0; nn < 8; ++nn)
                    acc2[m][nn] = __builtin_amdgcn_mfma_f32_16x16x32_bf16(bf2[nn], af2[m], acc2[m][nn], 0, 0, 0);
        }
#pragma unroll
        for (int m = 0; m < 2; ++m) {
            const int grow = m0 + wid * 32 + m * 16 + lrow;
            if (grow < n) {
#pragma unroll
                for (int nn = 0; nn < 8; ++nn) {
                    const int colb = nn * 16 + lq * 4;
                    const float4 bv = *(const float4*)(bdec + colb);
                    *(float4*)(dxp + (size_t)grow * NFEAT + colb) =
                        make_float4(acc2[m][nn][0] + bv.x, acc2[m][nn][1] + bv.y,
                                    acc2[m][nn][2] + bv.z, acc2[m][nn][3] + bv.w);
                }
            }
        }
    }
}

extern "C" void kernel_launch(void* const* d_in, const int* in_sizes, int n_in,
                              void* d_out, int out_size, void* d_ws, size_t ws_size,
                              hipStream_t stream) {
    const float* x     = (const float*)d_in[0];
    const int*   xedge = (const int*)d_in[1];
    const float* w1_l  = (const float*)d_in[2];
    const float* b1_l  = (const float*)d_in[3];
    const float* w1_r  = (const float*)d_in[4];
    const float* w2_l  = (const float*)d_in[5];
    const float* b2_l  = (const float*)d_in[6];
    const float* w2_r  = (const float*)d_in[7];
    const float* w_dec = (const float*)d_in[8];
    const float* b_dec = (const float*)d_in[9];

    const int N = in_sizes[0] / NFEAT;
    const int E = in_sizes[1] / 2;
    const int* src = xedge;
    const int* dst = xedge + E;

    float* h_out = (float*)d_out;                 // output 0: h  [N,128] fp32
    float* dxp   = h_out + (size_t)N * NFEAT;     // output 1: dx [N,128] fp32

    // ws: x_bf | h1_bf | mean_bf | wc1 | wc2 | wdec | deg | row_off | pos | bsum | perm
    char* ws = (char*)d_ws;
    ushort* x_bf    = (ushort*)ws;
    ushort* h1_bf   = x_bf   + (size_t)N * NFEAT;
    ushort* mean_bf = h1_bf  + (size_t)N * NFEAT;
    ushort* wc1     = mean_bf + (size_t)N * NFEAT;
    ushort* wc2     = wc1 + 128 * 256;
    ushort* wdec    = wc2 + 128 * 256;
    int* deg        = (int*)(wdec + 128 * 128);
    int* row_off    = deg + N;
    int* pos        = row_off + (N + 1);
    int* bsum       = pos + N;
    int* perm       = bsum + 256;

    // ---- prep: convert + weights + degree histogram in one launch ----
    hipMemsetAsync(deg, 0, (size_t)N * sizeof(int), stream);
    const long nx = (long)N * NFEAT;
    const int nCvt = (int)((nx / 4 + 255) / 256);
    const int histB = (E + 255) / 256;
    prep<<<nCvt + 320 + histB, 256, 0, stream>>>(x, x_bf, nx, w1_l, w1_r, w2_l, w2_r, w_dec,
                                                 wc1, wc2, wdec, dst, deg, E, nCvt);

    // ---- CSR build (by dst), reused by both layers ----
    const int nb = (N + 1023) / 1024;            // must be <= 128 for scan_add's 2-load carry
    scan_blocks<<<nb, 256, 0, stream>>>(deg, row_off, bsum, N);
    scan_add<<<(N + 255) / 256, 256, 0, stream>>>(row_off, pos, bsum, N, E);
    fill_csr<<<histB, 256, 0, stream>>>(src, dst, pos, perm, E);

    const int gb = (N + 127) / 128;
    const int ngroups = (N + 1) / 2;
    const int ggb = (ngroups * 16 + 255) / 256;   // 2 nodes per 16-lane group

    // ---- layer 1 ----
    gather_mean_bf<<<ggb, 256, 0, stream>>>(row_off, perm, x_bf, mean_bf, N);
    sage_mfma<true, false><<<gb, 256, 0, stream>>>(mean_bf, x_bf, wc1, b1_l,
                                                   nullptr, nullptr, nullptr, h1_bf, nullptr, N);

    // ---- layer 2 + fused decoder ----
    gather_mean_bf<<<ggb, 256, 0, stream>>>(row_off, perm, h1_bf, mean_bf, N);
    sage_mfma<false, true><<<gb, 256, 0, stream>>>(mean_bf, h1_bf, wc2, b2_l,
                                                   wdec, b_dec, h_out, nullptr, dxp, N);

    (void)n_in; (void)out_size; (void)ws_size;
}

// Round 15
// 199.732 us; speedup vs baseline: 1.0526x; 1.0526x over previous
//
#include <hip/hip_runtime.h>

typedef __attribute__((ext_vector_type(8))) short bf16x8;
typedef __attribute__((ext_vector_type(4))) float f32x4;
typedef unsigned int uint;
typedef unsigned short ushort;

#define NFEAT 128

__device__ __forceinline__ ushort f2b(float f) {
    uint u = __float_as_uint(f);
    u = (u + 0x7fffu + ((u >> 16) & 1u)) >> 16;   // RNE
    return (ushort)u;
}

// async global->LDS, 16B per lane; lds base must be wave-uniform (HW adds lane*16)
__device__ __forceinline__ void gload_lds16(const ushort* g, char* lds) {
    __builtin_amdgcn_global_load_lds((const __attribute__((address_space(1))) void*)g,
                                     (__attribute__((address_space(3))) void*)lds, 16, 0, 0);
}

// ---------------- merged prep: x->bf16 convert | weight prep | degree histogram ----
__global__ __launch_bounds__(256) void prep(
    const float* __restrict__ x, ushort* __restrict__ x_bf, long nx,
    const float* __restrict__ w1l, const float* __restrict__ w1r,
    const float* __restrict__ w2l, const float* __restrict__ w2r,
    const float* __restrict__ wd,
    ushort* __restrict__ wc1, ushort* __restrict__ wc2, ushort* __restrict__ wdec,
    const int* __restrict__ dst, int* __restrict__ deg, int E, int nCvt)
{
    const int b = blockIdx.x;
    if (b < nCvt) {
        long i = ((long)b * 256 + threadIdx.x) * 4;
        if (i < nx) {
            float4 v = *(const float4*)(x + i);
            ushort4 o;
            o.x = f2b(v.x); o.y = f2b(v.y); o.z = f2b(v.z); o.w = f2b(v.w);
            *(ushort4*)(x_bf + i) = o;
        }
    } else if (b < nCvt + 256) {
        const int bb = b - nCvt;
        const int i = (bb & 127) * 256 + threadIdx.x;
        const int row = i >> 8, col = i & 255;
        const float* wl = (bb < 128) ? w1l : w2l;
        const float* wr = (bb < 128) ? w1r : w2r;
        ushort* dstw = (bb < 128) ? wc1 : wc2;
        float v = (col < 128) ? wl[row * 128 + col] : wr[row * 128 + col - 128];
        dstw[i] = f2b(v);
    } else if (b < nCvt + 320) {
        const int i = (b - nCvt - 256) * 256 + threadIdx.x;   // 64*256 = 16384
        wdec[i] = f2b(wd[i]);
    } else {
        const int e = (b - nCvt - 320) * 256 + threadIdx.x;
        if (e < E) atomicAdd(&deg[dst[e]], 1);
    }
}

// ---------------- exclusive scan: block-local pass ----------------
__global__ __launch_bounds__(256) void scan_blocks(const int* __restrict__ in, int* __restrict__ out,
                                                   int* __restrict__ bsum, int n) {
    __shared__ int lds[256];
    const int t = threadIdx.x;
    const int base = blockIdx.x * 1024 + t * 4;
    int a[4];
#pragma unroll
    for (int q = 0; q < 4; ++q) a[q] = (base + q < n) ? in[base + q] : 0;
    const int tsum = a[0] + a[1] + a[2] + a[3];
    lds[t] = tsum;
    __syncthreads();
    for (int off = 1; off < 256; off <<= 1) {
        int v = (t >= off) ? lds[t - off] : 0;
        __syncthreads();
        lds[t] += v;
        __syncthreads();
    }
    const int excl = lds[t] - tsum;
    if (t == 255) bsum[blockIdx.x] = lds[255];
    int r = excl;
#pragma unroll
    for (int q = 0; q < 4; ++q) {
        if (base + q < n) out[base + q] = r;
        r += a[q];
    }
}

// ---------------- scan finalize: inline carry (wave all-reduce over bsum prefix) ----
__global__ __launch_bounds__(256) void scan_add(int* __restrict__ row_off, int* __restrict__ pos,
                                                const int* __restrict__ bsum, int n, int E) {
    const int i = blockIdx.x * 256 + threadIdx.x;
    const int cb = blockIdx.x >> 2;
    const int lane = threadIdx.x & 63;
    int v = 0;
    if (lane < cb) v += bsum[lane];
    if (lane + 64 < cb) v += bsum[lane + 64];
#pragma unroll
    for (int off = 1; off < 64; off <<= 1) v += __shfl_xor(v, off);
    if (i < n) {
        const int r = row_off[i] + v;
        row_off[i] = r;
        pos[i] = r;
    }
    if (i == 0) row_off[n] = E;
}

// ---------------- CSR bucket fill ----------------
__global__ void fill_csr(const int* __restrict__ src, const int* __restrict__ dst,
                         int* __restrict__ pos, int* __restrict__ perm, int E) {
    const int e = blockIdx.x * blockDim.x + threadIdx.x;
    if (e < E) {
        const int p = atomicAdd(&pos[dst[e]], 1);
        perm[p] = src[e];
    }
}

// ---------------- gather mean: one 16-lane group per node, 4-deep unroll ----------
__global__ __launch_bounds__(256) void gather_mean_bf(const int* __restrict__ row_off,
                                                      const int* __restrict__ perm,
                                                      const ushort* __restrict__ feat,
                                                      ushort* __restrict__ out, int n) {
    const int node = (blockIdx.x * 256 + threadIdx.x) >> 4;
    if (node >= n) return;
    const int chunk = threadIdx.x & 15;
    const int lo = row_off[node], hi = row_off[node + 1];
    float acc[8] = {0.f, 0.f, 0.f, 0.f, 0.f, 0.f, 0.f, 0.f};
    int i = lo;
    for (; i + 3 < hi; i += 4) {
        const int s0 = perm[i], s1 = perm[i + 1], s2 = perm[i + 2], s3 = perm[i + 3];
        const uint4 v0 = *(const uint4*)(feat + (size_t)s0 * NFEAT + chunk * 8);
        const uint4 v1 = *(const uint4*)(feat + (size_t)s1 * NFEAT + chunk * 8);
        const uint4 v2 = *(const uint4*)(feat + (size_t)s2 * NFEAT + chunk * 8);
        const uint4 v3 = *(const uint4*)(feat + (size_t)s3 * NFEAT + chunk * 8);
        const uint p0[4] = {v0.x, v0.y, v0.z, v0.w};
        const uint p1[4] = {v1.x, v1.y, v1.z, v1.w};
        const uint p2[4] = {v2.x, v2.y, v2.z, v2.w};
        const uint p3[4] = {v3.x, v3.y, v3.z, v3.w};
#pragma unroll
        for (int q = 0; q < 4; ++q) {
            acc[2 * q]     += __uint_as_float(p0[q] << 16) + __uint_as_float(p1[q] << 16)
                            + __uint_as_float(p2[q] << 16) + __uint_as_float(p3[q] << 16);
            acc[2 * q + 1] += __uint_as_float(p0[q] & 0xffff0000u) + __uint_as_float(p1[q] & 0xffff0000u)
                            + __uint_as_float(p2[q] & 0xffff0000u) + __uint_as_float(p3[q] & 0xffff0000u);
        }
    }
    for (; i < hi; ++i) {
        const int s = perm[i];
        const uint4 v = *(const uint4*)(feat + (size_t)s * NFEAT + chunk * 8);
        const uint p[4] = {v.x, v.y, v.z, v.w};
#pragma unroll
        for (int q = 0; q < 4; ++q) {
            acc[2 * q]     += __uint_as_float(p[q] << 16);
            acc[2 * q + 1] += __uint_as_float(p[q] & 0xffff0000u);
        }
    }
    const float inv = 1.0f / fmaxf((float)(hi - lo), 1.0f);
    ushort o[8] __attribute__((aligned(16)));
#pragma unroll
    for (int q = 0; q < 8; ++q) o[q] = f2b(acc[q] * inv);
    *(uint4*)(out + (size_t)node * NFEAT + chunk * 8) = *(const uint4*)o;
}

// ---------------- bf16 MFMA GEMM (staged via global_load_lds) + optional decoder ----
// out[row][col] = sum_k A[row][k] * Wcat[col][k] + bias[col]   (A = [mean|xin], K=256)
// Staging: global_load_lds width=16, LINEAR LDS dest (wave base + lane*16), the
// XOR-swizzle applied to the GLOBAL source chunk index (c = pc ^ (row&7)) so the
// swizzled ds_read side is unchanged (rule: both-sides-or-neither).
// Swapped MFMA operands: C layout row=lane&15 (node row), col=(lane>>4)*4+reg.
template <bool RELU, bool DEC>
__global__ __launch_bounds__(256) void sage_mfma(
    const ushort* __restrict__ Amean, const ushort* __restrict__ Axin,
    const ushort* __restrict__ Wcat, const float* __restrict__ bias,
    const ushort* __restrict__ Wdec, const float* __restrict__ bdec,
    float* __restrict__ outf, ushort* __restrict__ outb,
    float* __restrict__ dxp, int n)
{
    __shared__ uint4 smem4[2048];            // 32 KiB
    char* As = (char*)smem4;                 // [128 rows][64 bf16] swizzled
    char* Ws = As + 16384;
    const int t = threadIdx.x;
    const int m0 = blockIdx.x * 128;
    const int lane = t & 63;
    const int wid = t >> 6;
    const int lrow = lane & 15;
    const int lq = lane >> 4;

    f32x4 acc[2][8];
#pragma unroll
    for (int m = 0; m < 2; ++m)
#pragma unroll
        for (int nn = 0; nn < 8; ++nn) acc[m][nn] = (f32x4){0.f, 0.f, 0.f, 0.f};

    for (int kt = 0; kt < 4; ++kt) {
        const ushort* Abase = (kt < 2) ? Amean : Axin;
        const int co = (kt & 1) * 64;
        // ---- stage A and W tiles: 4 x 1KB wave-uniform chunks each
#pragma unroll
        for (int i = 0; i < 4; ++i) {
            const int row = i * 32 + wid * 8 + (lane >> 3);  // this lane's dest row
            const int c = (lane & 7) ^ (row & 7);            // pre-swizzled source chunk
            int gm = m0 + row;
            if (gm >= n) gm = n - 1;                         // clamp; masked at epilogue
            gload_lds16(Abase + (size_t)gm * NFEAT + co + c * 8,
                        As + i * 4096 + wid * 1024);
            gload_lds16(Wcat + (size_t)row * 256 + kt * 64 + c * 8,
                        Ws + i * 4096 + wid * 1024);
        }
        __syncthreads();
#pragma unroll
        for (int ks = 0; ks < 2; ++ks) {
            bf16x8 af[2], bfr[8];
#pragma unroll
            for (int m = 0; m < 2; ++m) {
                const int row = wid * 32 + m * 16 + lrow;
                af[m] = *(const bf16x8*)(As + row * 128 + (((ks * 4 + lq) * 16) ^ ((row & 7) << 4)));
            }
#pragma unroll
            for (int nn = 0; nn < 8; ++nn) {
                const int row = nn * 16 + lrow;
                bfr[nn] = *(const bf16x8*)(Ws + row * 128 + (((ks * 4 + lq) * 16) ^ ((row & 7) << 4)));
            }
#pragma unroll
            for (int m = 0; m < 2; ++m)
#pragma unroll
                for (int nn = 0; nn < 8; ++nn)
                    acc[m][nn] = __builtin_amdgcn_mfma_f32_16x16x32_bf16(bfr[nn], af[m], acc[m][nn], 0, 0, 0);
        }
        __syncthreads();
    }
    // ---- h epilogue (swapped C layout): node row = lane&15, cols = lq*4 + r
    char* Lh = As;   // DEC: [128 rows][128 bf16] swizzled, wave-private quarters
#pragma unroll
    for (int m = 0; m < 2; ++m) {
        const int row = wid * 32 + m * 16 + lrow;
        const int grow = m0 + row;
#pragma unroll
        for (int nn = 0; nn < 8; ++nn) {
            const int colb = nn * 16 + lq * 4;
            const float4 bv = *(const float4*)(bias + colb);
            float v0 = acc[m][nn][0] + bv.x;
            float v1 = acc[m][nn][1] + bv.y;
            float v2 = acc[m][nn][2] + bv.z;
            float v3 = acc[m][nn][3] + bv.w;
            if (RELU) {
                v0 = fmaxf(v0, 0.f); v1 = fmaxf(v1, 0.f);
                v2 = fmaxf(v2, 0.f); v3 = fmaxf(v3, 0.f);
            }
            ushort4 ob;
            ob.x = f2b(v0); ob.y = f2b(v1); ob.z = f2b(v2); ob.w = f2b(v3);
            if (grow < n) {
                if (outf) *(float4*)(outf + (size_t)grow * NFEAT + colb) = make_float4(v0, v1, v2, v3);
                if (outb) *(ushort4*)(outb + (size_t)grow * NFEAT + colb) = ob;
            }
            if (DEC)
                *(ushort4*)(Lh + row * 256 + ((colb * 2) ^ ((row & 7) << 4))) = ob;
        }
    }
    if (DEC) {
        // wave-private quarters: no barrier needed
        f32x4 acc2[2][8];
#pragma unroll
        for (int m = 0; m < 2; ++m)
#pragma unroll
            for (int nn = 0; nn < 8; ++nn) acc2[m][nn] = (f32x4){0.f, 0.f, 0.f, 0.f};
#pragma unroll
        for (int ks = 0; ks < 4; ++ks) {
            bf16x8 af2[2], bf2[8];
#pragma unroll
            for (int m = 0; m < 2; ++m) {
                const int row = wid * 32 + m * 16 + lrow;
                af2[m] = *(const bf16x8*)(Lh + row * 256 + ((ks * 64 + lq * 16) ^ ((row & 7) << 4)));
            }
#pragma unroll
            for (int nn = 0; nn < 8; ++nn)
                bf2[nn] = *(const bf16x8*)(Wdec + (size_t)(nn * 16 + lrow) * NFEAT + ks * 32 + lq * 8);
#pragma unroll
            for (int m = 0; m < 2; ++m)
#pragma unroll
                for (int nn = 0; nn < 8; ++nn)
                    acc2[m][nn] = __builtin_amdgcn_mfma_f32_16x16x32_bf16(bf2[nn], af2[m], acc2[m][nn], 0, 0, 0);
        }
#pragma unroll
        for (int m = 0; m < 2; ++m) {
            const int grow = m0 + wid * 32 + m * 16 + lrow;
            if (grow < n) {
#pragma unroll
                for (int nn = 0; nn < 8; ++nn) {
                    const int colb = nn * 16 + lq * 4;
                    const float4 bv = *(const float4*)(bdec + colb);
                    *(float4*)(dxp + (size_t)grow * NFEAT + colb) =
                        make_float4(acc2[m][nn][0] + bv.x, acc2[m][nn][1] + bv.y,
                                    acc2[m][nn][2] + bv.z, acc2[m][nn][3] + bv.w);
                }
            }
        }
    }
}

extern "C" void kernel_launch(void* const* d_in, const int* in_sizes, int n_in,
                              void* d_out, int out_size, void* d_ws, size_t ws_size,
                              hipStream_t stream) {
    const float* x     = (const float*)d_in[0];
    const int*   xedge = (const int*)d_in[1];
    const float* w1_l  = (const float*)d_in[2];
    const float* b1_l  = (const float*)d_in[3];
    const float* w1_r  = (const float*)d_in[4];
    const float* w2_l  = (const float*)d_in[5];
    const float* b2_l  = (const float*)d_in[6];
    const float* w2_r  = (const float*)d_in[7];
    const float* w_dec = (const float*)d_in[8];
    const float* b_dec = (const float*)d_in[9];

    const int N = in_sizes[0] / NFEAT;
    const int E = in_sizes[1] / 2;
    const int* src = xedge;
    const int* dst = xedge + E;

    float* h_out = (float*)d_out;                 // output 0: h  [N,128] fp32
    float* dxp   = h_out + (size_t)N * NFEAT;     // output 1: dx [N,128] fp32

    // ws: x_bf | h1_bf | mean_bf | wc1 | wc2 | wdec | deg | row_off | pos | bsum | perm
    char* ws = (char*)d_ws;
    ushort* x_bf    = (ushort*)ws;
    ushort* h1_bf   = x_bf   + (size_t)N * NFEAT;
    ushort* mean_bf = h1_bf  + (size_t)N * NFEAT;
    ushort* wc1     = mean_bf + (size_t)N * NFEAT;
    ushort* wc2     = wc1 + 128 * 256;
    ushort* wdec    = wc2 + 128 * 256;
    int* deg        = (int*)(wdec + 128 * 128);
    int* row_off    = deg + N;
    int* pos        = row_off + (N + 1);
    int* bsum       = pos + N;
    int* perm       = bsum + 256;

    // ---- prep: convert + weights + degree histogram in one launch ----
    hipMemsetAsync(deg, 0, (size_t)N * sizeof(int), stream);
    const long nx = (long)N * NFEAT;
    const int nCvt = (int)((nx / 4 + 255) / 256);
    const int histB = (E + 255) / 256;
    prep<<<nCvt + 320 + histB, 256, 0, stream>>>(x, x_bf, nx, w1_l, w1_r, w2_l, w2_r, w_dec,
                                                 wc1, wc2, wdec, dst, deg, E, nCvt);

    // ---- CSR build (by dst), reused by both layers ----
    const int nb = (N + 1023) / 1024;            // must be <= 128 for scan_add's 2-load carry
    scan_blocks<<<nb, 256, 0, stream>>>(deg, row_off, bsum, N);
    scan_add<<<(N + 255) / 256, 256, 0, stream>>>(row_off, pos, bsum, N, E);
    fill_csr<<<histB, 256, 0, stream>>>(src, dst, pos, perm, E);

    const int gb = (N + 127) / 128;
    const int ggb = (N * 16 + 255) / 256;

    // ---- layer 1 ----
    gather_mean_bf<<<ggb, 256, 0, stream>>>(row_off, perm, x_bf, mean_bf, N);
    sage_mfma<true, false><<<gb, 256, 0, stream>>>(mean_bf, x_bf, wc1, b1_l,
                                                   nullptr, nullptr, nullptr, h1_bf, nullptr, N);

    // ---- layer 2 + fused decoder ----
    gather_mean_bf<<<ggb, 256, 0, stream>>>(row_off, perm, h1_bf, mean_bf, N);
    sage_mfma<false, true><<<gb, 256, 0, stream>>>(mean_bf, h1_bf, wc2, b2_l,
                                                   wdec, b_dec, h_out, nullptr, dxp, N);

    (void)n_in; (void)out_size; (void)ws_size;
}